// Round 7
// baseline (174.988 us; speedup 1.0000x reference)
//
#include <hip/hip_runtime.h>
#include <math.h>

#define SEQ 4096
#define DMODEL 1024
#define NHEADS 16
#define HDIM 64

typedef __bf16 v8bf __attribute__((ext_vector_type(8)));
typedef float f32x4 __attribute__((ext_vector_type(4)));
typedef float f32x16 __attribute__((ext_vector_type(16)));
typedef int i32x2 __attribute__((ext_vector_type(2)));
typedef int i32x4 __attribute__((ext_vector_type(4)));

#define NPART 4608   // partial chunks (qb>=32): 16 heads * 288
#define SCALE_Q 0.18033688011112042f   // 0.125 * log2(e), folded into Q at proj

__device__ __forceinline__ unsigned short f2bf(float f) {
    union { float f; unsigned int u; } v; v.f = f;
    unsigned int u = v.u;
    return (unsigned short)((u + 0x7fffu + ((u >> 16) & 1u)) >> 16);
}

__device__ __forceinline__ int cvtpk(float lo, float hi) {
    int r;
    asm("v_cvt_pk_bf16_f32 %0, %1, %2" : "=v"(r) : "v"(lo), "v"(hi));
    return r;
}

// async global->LDS, 16B per lane; LDS dest = wave-uniform base + lane*16
__device__ __forceinline__ void gload16(const float* g, float* l) {
    __builtin_amdgcn_global_load_lds(
        (const __attribute__((address_space(1))) float*)g,
        (__attribute__((address_space(3))) float*)l, 16, 0, 0);
}

// ---------------------------------------------------------------------------
// Kernel 1: projection GEMM  C = X @ W^T, bf16 MFMA, fp32 inputs.
// Staging: global_load_lds width=16 direct to LDS (fp32, no VGPR round-trip).
// LDS linear dest + inverse-swizzled global SOURCE (blk ^ (row&7)) +
// same XOR on fragment read (rule 21 both-sides).  bf16 conversion happens
// at fragment read via v_cvt_pk_bf16_f32 (RNE, identical values to f2bf).
//   z=0: qh[h][s][64] bf16, RoPE'd, PRE-SCALED by 0.125*log2(e)
//   z=1: kh[h][s][64] bf16, RoPE'd
//   z=2: vht[h][64][s] bf16 transposed
// ---------------------------------------------------------------------------
__global__ __launch_bounds__(256) void proj_rope_kernel(
    const float* __restrict__ Xq, const float* __restrict__ Xk, const float* __restrict__ Xv,
    const float* __restrict__ Wq, const float* __restrict__ Wk, const float* __restrict__ Wv,
    unsigned short* __restrict__ qh, unsigned short* __restrict__ kh,
    unsigned short* __restrict__ vht)
{
    const int tz = blockIdx.z;
    const float* __restrict__ X = (tz == 0) ? Xq : (tz == 1) ? Xk : Xv;
    const float* __restrict__ W = (tz == 0) ? Wq : (tz == 1) ? Wk : Wv;

    const int tid = threadIdx.x;
    const int lane = tid & 63;
    const int wid = tid >> 6;
    const int l15 = lane & 15;
    const int l4 = lane >> 4;
    const int wr = wid >> 1, wc = wid & 1;

    const int m0 = blockIdx.x * 128;
    const int n0 = blockIdx.y * 128;

    __shared__ __align__(16) float Ab[128 * 32];   // 16 KB, fp32, swizzled content
    __shared__ __align__(16) float Bb[128 * 32];   // 16 KB

    // staging source precompute: linear LDS pos p = wid*4096 + c*1024 + lane*16
    //   row = wid*32 + c*8 + (lane>>3); blk_lin = lane&7; src_blk = blk_lin^(row&7)
    int rowc[4], colc[4];
    #pragma unroll
    for (int c = 0; c < 4; ++c) {
        int row = wid * 32 + c * 8 + (lane >> 3);
        int blk = (lane & 7) ^ (row & 7);
        rowc[c] = row;
        colc[c] = blk * 4;          // fp32 elem offset within the 32-wide k-slab
    }

    f32x4 acc[4][4] = {};

    for (int kt = 0; kt < 32; ++kt) {
        if (kt > 0) __syncthreads();          // previous tile's reads done
        const int k0 = kt << 5;
        #pragma unroll
        for (int c = 0; c < 4; ++c) {
            const float* ga = X + (size_t)(m0 + rowc[c]) * DMODEL + k0 + colc[c];
            const float* gb = W + (size_t)(n0 + rowc[c]) * DMODEL + k0 + colc[c];
            float* la = Ab + (wid * 1024 + c * 256);    // fp32 elems: 4096B/4
            float* lb = Bb + (wid * 1024 + c * 256);
            gload16(ga, la);
            gload16(gb, lb);
        }
        __syncthreads();                      // vmcnt drain + all waves staged

        // fragment read: row*128B + ((2*l4+j)^(row&7))*16B, cvt to bf16
        v8bf af[4], bfr[4];
        #pragma unroll
        for (int mi = 0; mi < 4; ++mi) {
            int row = wr * 64 + mi * 16 + l15;
            const char* base = reinterpret_cast<const char*>(Ab) + row * 128;
            f32x4 lo = *reinterpret_cast<const f32x4*>(base + ((((l4 << 1)    ) ^ (row & 7)) << 4));
            f32x4 hi = *reinterpret_cast<const f32x4*>(base + ((((l4 << 1) | 1) ^ (row & 7)) << 4));
            i32x4 u;
            u.x = cvtpk(lo[0], lo[1]); u.y = cvtpk(lo[2], lo[3]);
            u.z = cvtpk(hi[0], hi[1]); u.w = cvtpk(hi[2], hi[3]);
            v8bf r; __builtin_memcpy(&r, &u, 16);
            af[mi] = r;
        }
        #pragma unroll
        for (int ni = 0; ni < 4; ++ni) {
            int row = wc * 64 + ni * 16 + l15;
            const char* base = reinterpret_cast<const char*>(Bb) + row * 128;
            f32x4 lo = *reinterpret_cast<const f32x4*>(base + ((((l4 << 1)    ) ^ (row & 7)) << 4));
            f32x4 hi = *reinterpret_cast<const f32x4*>(base + ((((l4 << 1) | 1) ^ (row & 7)) << 4));
            i32x4 u;
            u.x = cvtpk(lo[0], lo[1]); u.y = cvtpk(lo[2], lo[3]);
            u.z = cvtpk(hi[0], hi[1]); u.w = cvtpk(hi[2], hi[3]);
            v8bf r; __builtin_memcpy(&r, &u, 16);
            bfr[ni] = r;
        }
        #pragma unroll
        for (int mi = 0; mi < 4; ++mi)
            #pragma unroll
            for (int ni = 0; ni < 4; ++ni)
                acc[mi][ni] = __builtin_amdgcn_mfma_f32_16x16x32_bf16(af[mi], bfr[ni], acc[mi][ni], 0, 0, 0);
    }

    const int h = (n0 >> 6) + wc;
    const int mbase = m0 + wr * 64;
    if (tz == 2) {
        unsigned short* base = vht + (size_t)h * HDIM * SEQ;
        #pragma unroll
        for (int mi = 0; mi < 4; ++mi) {
            #pragma unroll
            for (int ni = 0; ni < 4; ++ni) {
                int d = ni * 16 + l15;
                int m = mbase + mi * 16 + l4 * 4;
                uint2 pk;
                pk.x = (unsigned)f2bf(acc[mi][ni][0]) | ((unsigned)f2bf(acc[mi][ni][1]) << 16);
                pk.y = (unsigned)f2bf(acc[mi][ni][2]) | ((unsigned)f2bf(acc[mi][ni][3]) << 16);
                *reinterpret_cast<uint2*>(base + (size_t)d * SEQ + m) = pk;
            }
        }
    } else {
        unsigned short* base = ((tz == 0) ? qh : kh) + (size_t)h * SEQ * HDIM;
        const float scl = (tz == 0) ? SCALE_Q : 1.0f;   // fold softmax scale into Q
        #pragma unroll
        for (int ni = 0; ni < 2; ++ni) {
            int j = ni * 16 + l15;
            float invf = expf(-(float)j * 0.28782313662425574f);  // ln(10000)/32
            #pragma unroll
            for (int mi = 0; mi < 4; ++mi) {
                #pragma unroll
                for (int r = 0; r < 4; ++r) {
                    int m = mbase + mi * 16 + l4 * 4 + r;
                    float ang = (float)m * invf;
                    float sn, cs;
                    sincosf(ang, &sn, &cs);
                    sn *= scl; cs *= scl;
                    float x1 = acc[mi][ni][r];
                    float x2 = acc[mi][ni + 2][r];
                    base[(size_t)m * HDIM + j]      = f2bf(x1 * cs - x2 * sn);
                    base[(size_t)m * HDIM + j + 32] = f2bf(x1 * sn + x2 * cs);
                }
            }
        }
    }
}

// ---------------------------------------------------------------------------
// Kernel 2: repack K and V into MFMA-fragment order (one-shot gather).
//   kfr[h][T][ns*4+dk][lane][8] : lane holds K[T*64+ns*32+l31][dk*16+l5*8+j]
//   vfr[h][T][dt*4+kb][lane][8] : lane holds V^T[dt*32+l31][T*64+kb*16+l5*8+j]
// In attention every fragment load becomes base+lane*16B = dense 1KB.
// ---------------------------------------------------------------------------
__global__ __launch_bounds__(256) void repack_kernel(
    const unsigned short* __restrict__ kh, const unsigned short* __restrict__ vht,
    unsigned short* __restrict__ kfr, unsigned short* __restrict__ vfr)
{
    const int lane = threadIdx.x & 63;
    const int wid = threadIdx.x >> 6;
    const int l31 = lane & 31;
    const int l5 = lane >> 5;
    const int h = blockIdx.x >> 4;
    const int T = ((blockIdx.x & 15) << 2) + wid;

    const unsigned short* __restrict__ ksrc = kh + ((size_t)h * SEQ + T * 64) * HDIM;
    unsigned short* __restrict__ kdst = kfr + ((size_t)(h * 64 + T)) * 4096 + lane * 8;
    #pragma unroll
    for (int ns = 0; ns < 2; ++ns)
        #pragma unroll
        for (int dk = 0; dk < 4; ++dk) {
            v8bf f = *reinterpret_cast<const v8bf*>(ksrc + (ns * 32 + l31) * HDIM + dk * 16 + l5 * 8);
            *reinterpret_cast<v8bf*>(kdst + (ns * 4 + dk) * 512) = f;
        }

    const unsigned short* __restrict__ vsrc = vht + ((size_t)h * 64) * SEQ;
    unsigned short* __restrict__ vdst = vfr + ((size_t)(h * 64 + T)) * 4096 + lane * 8;
    #pragma unroll
    for (int dt = 0; dt < 2; ++dt)
        #pragma unroll
        for (int kb = 0; kb < 4; ++kb) {
            v8bf f = *reinterpret_cast<const v8bf*>(
                vsrc + (size_t)(dt * 32 + l31) * SEQ + T * 64 + kb * 16 + l5 * 8);
            *reinterpret_cast<v8bf*>(vdst + (dt * 4 + kb) * 512) = f;
        }
}

// ---------------------------------------------------------------------------
// Kernel 3: causal flash attention, swapped-QK^T 32x32, flash-decoding split.
// 1 wave/block, 32 q-rows, KV chunk of <=16 rounds (1024 kv) per wave.
// 5120 balanced waves, no LDS, no barriers. K/V fragment loads are DENSE
// (pre-fragmented kfr/vfr): base + lane*16B, one 1KB instr per fragment.
// ---------------------------------------------------------------------------
__global__ __launch_bounds__(64, 2) void attn_kernel(
    const unsigned short* __restrict__ qh, const unsigned short* __restrict__ kfr,
    const unsigned short* __restrict__ vfr, float* __restrict__ out,
    unsigned short* __restrict__ po, float* __restrict__ ml)
{
    const int lane = threadIdx.x & 63;
    const int l31 = lane & 31;
    const int l5 = lane >> 5;

    const int bid = blockIdx.x;
    const int xcd = bid & 7;                 // HW: consecutive bids round-robin XCDs
    const int idx = bid >> 3;                // 0..639 per XCD
    const int hsel = (idx >= 320) ? 1 : 0;
    const int h = (xcd << 1) | hsel;         // 2 heads per XCD -> K/V L2-resident
    const int r = 319 - (idx - hsel * 320);  // descending: long chunks first

    int qb, c, nc;
    if (r < 32)       { qb = r;                     c = 0;            nc = 1; }
    else if (r < 96)  { qb = 32 + ((r - 32) >> 1);  c = (r - 32) & 1; nc = 2; }
    else if (r < 192) { int rr = r - 96; qb = 64 + rr / 3; c = rr - (qb - 64) * 3; nc = 3; }
    else              { int rr = r - 192; qb = 96 + (rr >> 2); c = rr & 3; nc = 4; }

    const int q0 = qb * 32;
    const int q = q0 + l31;
    const int nt = (q0 + 32 + 63) >> 6;      // total kv-rounds for this q-tile
    const int t0 = c * 16;
    const int t1 = min(t0 + 16, nt);

    const unsigned short* __restrict__ qbase = qh + ((size_t)h * SEQ + q) * HDIM + l5 * 8;
    const unsigned short* __restrict__ kfh = kfr + (size_t)h * 262144 + lane * 8;
    const unsigned short* __restrict__ vfh = vfr + (size_t)h * 262144 + lane * 8;

    v8bf qf[4];
    #pragma unroll
    for (int dk = 0; dk < 4; ++dk)
        qf[dk] = *reinterpret_cast<const v8bf*>(qbase + dk * 16);

    f32x16 of[2] = {};
    float mreg = -INFINITY, lreg = 0.0f;

    auto LOADK = [&](v8bf (&KB)[8], int T) {
        const unsigned short* kp = kfh + (size_t)T * 4096;
        #pragma unroll
        for (int f = 0; f < 8; ++f)
            KB[f] = *reinterpret_cast<const v8bf*>(kp + f * 512);
    };

    auto ROUND = [&](int T, v8bf (&KC)[8], v8bf (&KN)[8]) {
        // V^T fragments (dense 1KB loads; issued early, consumed after softmax)
        v8bf vf[8];
        {
            const unsigned short* vp = vfh + (size_t)T * 4096;
            #pragma unroll
            for (int f = 0; f < 8; ++f)
                vf[f] = *reinterpret_cast<const v8bf*>(vp + f * 512);
        }
        if (T + 1 < t1) LOADK(KN, T + 1);

        // S^T = K Q^T : col=q=l31, row_kv = T*64 + 32ns + (i&3)+8*(i>>2)+4*l5
        f32x16 st[2];
        __builtin_amdgcn_s_setprio(1);
        #pragma unroll
        for (int ns = 0; ns < 2; ++ns) {
            f32x16 acc = {};
            #pragma unroll
            for (int dk = 0; dk < 4; ++dk)
                acc = __builtin_amdgcn_mfma_f32_32x32x16_bf16(KC[ns * 4 + dk], qf[dk], acc, 0, 0, 0);
            st[ns] = acc;
        }
        __builtin_amdgcn_s_setprio(0);

        // causal mask: provably needed only on the globally-last round
        if (T == nt - 1) {
            const int kvb = T * 64 + 4 * l5;
            #pragma unroll
            for (int ns = 0; ns < 2; ++ns)
                #pragma unroll
                for (int i = 0; i < 16; ++i) {
                    int kv = kvb + ns * 32 + (i & 3) + 8 * (i >> 2);
                    if (kv > q) st[ns][i] = -INFINITY;
                }
        }

        // row max: in-lane tree + 1 permlane32_swap
        float t16[16];
        #pragma unroll
        for (int i = 0; i < 16; ++i) t16[i] = fmaxf(st[0][i], st[1][i]);
        #pragma unroll
        for (int i = 0; i < 8; ++i) t16[i] = fmaxf(t16[i], t16[i + 8]);
        #pragma unroll
        for (int i = 0; i < 4; ++i) t16[i] = fmaxf(t16[i], t16[i + 4]);
        float pmax = fmaxf(fmaxf(t16[0], t16[1]), fmaxf(t16[2], t16[3]));
        {
            i32x2 sw = __builtin_amdgcn_permlane32_swap(__float_as_int(pmax), __float_as_int(pmax), false, false);
            pmax = fmaxf(__int_as_float(sw.x), __int_as_float(sw.y));
        }

        // defer-max (T13): rescale only if max grew by > 8 (exp2 domain)
        if (!__all(pmax - mreg <= 8.0f)) {
            float mnew = fmaxf(mreg, pmax);
            float sc = exp2f(mreg - mnew);
            lreg *= sc;
            #pragma unroll
            for (int dt = 0; dt < 2; ++dt)
                #pragma unroll
                for (int i = 0; i < 16; ++i) of[dt][i] *= sc;
            mreg = mnew;
        }

        // exp2 + partial row-sum
        float ps0 = 0.f, ps1 = 0.f, ps2 = 0.f, ps3 = 0.f;
        #pragma unroll
        for (int ns = 0; ns < 2; ++ns)
            #pragma unroll
            for (int i = 0; i < 16; ++i) {
                float p = exp2f(st[ns][i] - mreg);
                st[ns][i] = p;
                if ((i & 3) == 0) ps0 += p; else if ((i & 3) == 1) ps1 += p;
                else if ((i & 3) == 2) ps2 += p; else ps3 += p;
            }
        lreg += (ps0 + ps1) + (ps2 + ps3);

        // P^T B-fragments: cvt_pk + permlane32_swap (T12)
        v8bf pt[4];
        #pragma unroll
        for (int kb = 0; kb < 4; ++kb) {
            int ns = kb >> 1, kp = (kb & 1) * 8;
            int A0 = cvtpk(st[ns][kp + 0], st[ns][kp + 1]);
            int A1 = cvtpk(st[ns][kp + 2], st[ns][kp + 3]);
            int B0 = cvtpk(st[ns][kp + 4], st[ns][kp + 5]);
            int B1 = cvtpk(st[ns][kp + 6], st[ns][kp + 7]);
            i32x2 s0 = __builtin_amdgcn_permlane32_swap(A0, B0, false, false);
            i32x2 s1 = __builtin_amdgcn_permlane32_swap(A1, B1, false, false);
            i32x4 u; u.x = s0.x; u.y = s1.x; u.z = s0.y; u.w = s1.y;
            v8bf p; __builtin_memcpy(&p, &u, 16);
            pt[kb] = p;
        }

        // O^T += V^T P^T
        __builtin_amdgcn_s_setprio(1);
        #pragma unroll
        for (int dt = 0; dt < 2; ++dt)
            #pragma unroll
            for (int kb = 0; kb < 4; ++kb)
                of[dt] = __builtin_amdgcn_mfma_f32_32x32x16_bf16(vf[dt * 4 + kb], pt[kb], of[dt], 0, 0, 0);
        __builtin_amdgcn_s_setprio(0);
    };

    v8bf kA[8], kB[8];
    LOADK(kA, t0);
    int t = t0;
    while (true) {
        ROUND(t, kA, kB);
        if (++t == t1) break;
        ROUND(t, kB, kA);
        if (++t == t1) break;
    }

    // pair-sum l across halves (both halves end with full row-sum)
    {
        i32x2 sw = __builtin_amdgcn_permlane32_swap(__float_as_int(lreg), __float_as_int(lreg), false, false);
        lreg = __int_as_float(sw.x) + __int_as_float(sw.y);
    }

    if (nc == 1) {
        float inv = 1.0f / lreg;
        float* obase = out + (size_t)q * DMODEL + h * HDIM + l5 * 4;
        #pragma unroll
        for (int dt = 0; dt < 2; ++dt)
            #pragma unroll
            for (int g = 0; g < 4; ++g) {
                f32x4 o4;
                o4[0] = of[dt][g * 4 + 0] * inv;
                o4[1] = of[dt][g * 4 + 1] * inv;
                o4[2] = of[dt][g * 4 + 2] * inv;
                o4[3] = of[dt][g * 4 + 3] * inv;
                *reinterpret_cast<f32x4*>(obase + dt * 32 + g * 8) = o4;
            }
    } else {
        const int p = h * 288 + (r - 32);
        unsigned short* pb = po + ((size_t)p * 32 + l31) * 64 + l5 * 4;
        #pragma unroll
        for (int dt = 0; dt < 2; ++dt)
            #pragma unroll
            for (int g = 0; g < 4; ++g) {
                uint2 u;
                u.x = (unsigned)cvtpk(of[dt][g * 4 + 0], of[dt][g * 4 + 1]);
                u.y = (unsigned)cvtpk(of[dt][g * 4 + 2], of[dt][g * 4 + 3]);
                *reinterpret_cast<uint2*>(pb + dt * 32 + g * 8) = u;
            }
        if (l5 == 0) {
            float2 v; v.x = mreg; v.y = lreg;
            reinterpret_cast<float2*>(ml)[(size_t)p * 32 + l31] = v;
        }
    }
}

// ---------------------------------------------------------------------------
// Kernel 4: combine partials for qb>=32 (2..4 chunks per q-tile).
// 1536 blocks x 256 threads (4 rows in parallel).
// ---------------------------------------------------------------------------
__global__ __launch_bounds__(256) void combine_kernel(
    const unsigned short* __restrict__ po, const float* __restrict__ ml,
    float* __restrict__ out)
{
    const int b = blockIdx.x;
    const int h = b / 96;
    const int j = b - h * 96;
    const int qb = 32 + j;
    int nc, r0;
    if (qb < 64)      { nc = 2; r0 = 32 + ((qb - 32) << 1); }
    else if (qb < 96) { nc = 3; r0 = 96 + (qb - 64) * 3; }
    else              { nc = 4; r0 = 192 + ((qb - 96) << 2); }
    const int p0 = h * 288 + (r0 - 32);
    const int d = threadIdx.x & 63;
    const int rg = threadIdx.x >> 6;
    const int q0 = qb * 32;

    for (int row = rg; row < 32; row += 4) {
        float mc[4], lc[4];
        float M = -INFINITY;
        #pragma unroll
        for (int ci = 0; ci < 4; ++ci)
            if (ci < nc) {
                float2 v = reinterpret_cast<const float2*>(ml)[(size_t)(p0 + ci) * 32 + row];
                mc[ci] = v.x; lc[ci] = v.y;
                M = fmaxf(M, v.x);
            }
        float L = 0.0f, O = 0.0f;
        #pragma unroll
        for (int ci = 0; ci < 4; ++ci)
            if (ci < nc) {
                float w = exp2f(mc[ci] - M);
                L += lc[ci] * w;
                unsigned int raw = po[((size_t)(p0 + ci) * 32 + row) * 64 + d];
                union { unsigned int u; float f; } cv; cv.u = raw << 16;
                O += cv.f * w;
            }
        out[(size_t)(q0 + row) * DMODEL + h * HDIM + d] = O / L;
    }
}

extern "C" void kernel_launch(void* const* d_in, const int* in_sizes, int n_in,
                              void* d_out, int out_size, void* d_ws, size_t ws_size,
                              hipStream_t stream) {
    (void)in_sizes; (void)n_in; (void)out_size; (void)ws_size;
    const float* q  = (const float*)d_in[0];
    const float* k  = (const float*)d_in[1];
    const float* v  = (const float*)d_in[2];
    // d_in[3] = mask: tril(ones) -> causal, applied analytically
    const float* Wq = (const float*)d_in[4];
    const float* Wk = (const float*)d_in[5];
    const float* Wv = (const float*)d_in[6];

    // ws layout (po overlays kh+vht, which are dead after repack):
    unsigned short* qh  = (unsigned short*)d_ws;                      // 8.4 MB
    unsigned short* kfr = qh  + (size_t)NHEADS * SEQ * HDIM;          // 8.4 MB
    unsigned short* vfr = kfr + (size_t)NHEADS * SEQ * HDIM;          // 8.4 MB
    unsigned short* kh  = vfr + (size_t)NHEADS * SEQ * HDIM;          // 8.4 MB
    unsigned short* vht = kh  + (size_t)NHEADS * SEQ * HDIM;          // 8.4 MB
    unsigned short* po  = kh;                                         // 18.9 MB (overlay)
    float* ml = (float*)(po + (size_t)NPART * 32 * 64);               // 1.2 MB
    float* out = (float*)d_out;

    dim3 g1(SEQ / 128, DMODEL / 128, 3);
    proj_rope_kernel<<<g1, 256, 0, stream>>>(q, k, v, Wq, Wk, Wv, qh, kh, vht);

    repack_kernel<<<dim3(256), 256, 0, stream>>>(kh, vht, kfr, vfr);

    attn_kernel<<<dim3(16 * 320), 64, 0, stream>>>(qh, kfr, vfr, out, po, ml);

    combine_kernel<<<dim3(16 * 96), 256, 0, stream>>>(po, ml, out);
}

// Round 8
// 161.548 us; speedup vs baseline: 1.0832x; 1.0832x over previous
//
#include <hip/hip_runtime.h>
#include <math.h>

#define SEQ 4096
#define DMODEL 1024
#define NHEADS 16
#define HDIM 64

typedef __bf16 v8bf __attribute__((ext_vector_type(8)));
typedef float f32x4 __attribute__((ext_vector_type(4)));
typedef float f32x16 __attribute__((ext_vector_type(16)));
typedef int i32x2 __attribute__((ext_vector_type(2)));
typedef int i32x4 __attribute__((ext_vector_type(4)));

#define NPART 4608   // partial chunks (qb>=32): 16 heads * 288
#define SCALE_Q 0.18033688011112042f   // 0.125 * log2(e), folded into Q at proj

__device__ __forceinline__ unsigned short f2bf(float f) {
    union { float f; unsigned int u; } v; v.f = f;
    unsigned int u = v.u;
    return (unsigned short)((u + 0x7fffu + ((u >> 16) & 1u)) >> 16);
}

__device__ __forceinline__ int cvtpk(float lo, float hi) {
    int r;
    asm("v_cvt_pk_bf16_f32 %0, %1, %2" : "=v"(r) : "v"(lo), "v"(hi));
    return r;
}

// ---------------------------------------------------------------------------
// Kernel 1: projection GEMM  C = X @ W^T, bf16 MFMA, fp32 inputs.
// r6 structure (bf16 LDS, measured-0-conflict swizzle) + three fixes:
//  (a) staging pack via v_cvt_pk_bf16_f32 (1 instr / 2 elems, RNE == f2bf)
//  (b) LDS double-buffer -> ONE barrier per k-step (read buf[kt&1],
//      write buf[(kt+1)&1] -- disjoint within an interval)
//  (c) T14: global loads issued right AFTER the barrier, pack+write AFTER
//      the MFMA cluster -> latency hidden under compute.
//   z=0: qh[h][s][64] bf16, RoPE'd, PRE-SCALED by 0.125*log2(e)
//   z=1: kh[h][s][64] bf16, RoPE'd
//   z=2: vht[h][64][s] bf16 transposed
// ---------------------------------------------------------------------------
__global__ __launch_bounds__(256) void proj_rope_kernel(
    const float* __restrict__ Xq, const float* __restrict__ Xk, const float* __restrict__ Xv,
    const float* __restrict__ Wq, const float* __restrict__ Wk, const float* __restrict__ Wv,
    unsigned short* __restrict__ qh, unsigned short* __restrict__ kh,
    unsigned short* __restrict__ vht)
{
    const int tz = blockIdx.z;
    const float* __restrict__ X = (tz == 0) ? Xq : (tz == 1) ? Xk : Xv;
    const float* __restrict__ W = (tz == 0) ? Wq : (tz == 1) ? Wk : Wv;

    const int tid = threadIdx.x;
    const int lane = tid & 63;
    const int wid = tid >> 6;
    const int l15 = lane & 15;
    const int l4 = lane >> 4;
    const int wr = wid >> 1, wc = wid & 1;

    const int m0 = blockIdx.x * 128;
    const int n0 = blockIdx.y * 128;

    __shared__ __align__(16) unsigned short Ab[2][128 * 32];   // 8 KB each
    __shared__ __align__(16) unsigned short Bb[2][128 * 32];

    // staging coords (r6's proven conflict-free swizzle)
    int srow[4], sc4[4], sbyte[4];
    #pragma unroll
    for (int c = 0; c < 4; ++c) {
        int i = tid + (c << 8);
        int row = i >> 3;
        int c4 = (i & 7) << 2;                      // fp32 col within 32-slab
        srow[c] = row; sc4[c] = c4;
        sbyte[c] = row * 64 + (((c4 >> 3) ^ ((row >> 1) & 3)) << 4) + ((c4 << 1) & 15);
    }

    float4 ra[4], rb[4];

    auto GLOAD = [&](int kt) {
        const int k0 = kt << 5;
        #pragma unroll
        for (int c = 0; c < 4; ++c) {
            ra[c] = *reinterpret_cast<const float4*>(X + (size_t)(m0 + srow[c]) * DMODEL + k0 + sc4[c]);
            rb[c] = *reinterpret_cast<const float4*>(W + (size_t)(n0 + srow[c]) * DMODEL + k0 + sc4[c]);
        }
    };
    auto PACKW = [&](int b) {
        #pragma unroll
        for (int c = 0; c < 4; ++c) {
            uint2 pa, pb;
            pa.x = (unsigned)cvtpk(ra[c].x, ra[c].y);
            pa.y = (unsigned)cvtpk(ra[c].z, ra[c].w);
            pb.x = (unsigned)cvtpk(rb[c].x, rb[c].y);
            pb.y = (unsigned)cvtpk(rb[c].z, rb[c].w);
            *reinterpret_cast<uint2*>(reinterpret_cast<char*>(Ab[b]) + sbyte[c]) = pa;
            *reinterpret_cast<uint2*>(reinterpret_cast<char*>(Bb[b]) + sbyte[c]) = pb;
        }
    };

    f32x4 acc[4][4] = {};

    GLOAD(0);
    PACKW(0);

    for (int kt = 0; kt < 32; ++kt) {
        __syncthreads();                       // publishes buf[kt&1]
        const bool hn = (kt < 31);
        if (hn) GLOAD(kt + 1);                 // in flight under frag-reads+MFMA

        const unsigned short* A = Ab[kt & 1];
        const unsigned short* B = Bb[kt & 1];

        v8bf af[4], bfr[4];
        #pragma unroll
        for (int mi = 0; mi < 4; ++mi) {
            int row = wr * 64 + mi * 16 + l15;
            int byte = row * 64 + ((l4 ^ ((row >> 1) & 3)) << 4);
            af[mi] = *reinterpret_cast<const v8bf*>(reinterpret_cast<const char*>(A) + byte);
        }
        #pragma unroll
        for (int ni = 0; ni < 4; ++ni) {
            int row = wc * 64 + ni * 16 + l15;
            int byte = row * 64 + ((l4 ^ ((row >> 1) & 3)) << 4);
            bfr[ni] = *reinterpret_cast<const v8bf*>(reinterpret_cast<const char*>(B) + byte);
        }
        #pragma unroll
        for (int mi = 0; mi < 4; ++mi)
            #pragma unroll
            for (int ni = 0; ni < 4; ++ni)
                acc[mi][ni] = __builtin_amdgcn_mfma_f32_16x16x32_bf16(af[mi], bfr[ni], acc[mi][ni], 0, 0, 0);

        if (hn) PACKW((kt + 1) & 1);           // vmcnt wait lands here, post-MFMA
    }

    const int h = (n0 >> 6) + wc;
    const int mbase = m0 + wr * 64;
    if (tz == 2) {
        unsigned short* base = vht + (size_t)h * HDIM * SEQ;
        #pragma unroll
        for (int mi = 0; mi < 4; ++mi) {
            #pragma unroll
            for (int ni = 0; ni < 4; ++ni) {
                int d = ni * 16 + l15;
                int m = mbase + mi * 16 + l4 * 4;
                uint2 pk;
                pk.x = (unsigned)cvtpk(acc[mi][ni][0], acc[mi][ni][1]);
                pk.y = (unsigned)cvtpk(acc[mi][ni][2], acc[mi][ni][3]);
                *reinterpret_cast<uint2*>(base + (size_t)d * SEQ + m) = pk;
            }
        }
    } else {
        unsigned short* base = ((tz == 0) ? qh : kh) + (size_t)h * SEQ * HDIM;
        const float scl = (tz == 0) ? SCALE_Q : 1.0f;   // fold softmax scale into Q
        #pragma unroll
        for (int ni = 0; ni < 2; ++ni) {
            int j = ni * 16 + l15;
            float invf = expf(-(float)j * 0.28782313662425574f);  // ln(10000)/32
            #pragma unroll
            for (int mi = 0; mi < 4; ++mi) {
                #pragma unroll
                for (int r = 0; r < 4; ++r) {
                    int m = mbase + mi * 16 + l4 * 4 + r;
                    float ang = (float)m * invf;
                    float sn, cs;
                    sincosf(ang, &sn, &cs);
                    sn *= scl; cs *= scl;
                    float x1 = acc[mi][ni][r];
                    float x2 = acc[mi][ni + 2][r];
                    base[(size_t)m * HDIM + j]      = f2bf(x1 * cs - x2 * sn);
                    base[(size_t)m * HDIM + j + 32] = f2bf(x1 * sn + x2 * cs);
                }
            }
        }
    }
}

// ---------------------------------------------------------------------------
// Kernel 2: repack K and V into MFMA-fragment order (one-shot gather).
//   kfr[h][T][ns*4+dk][lane][8] : lane holds K[T*64+ns*32+l31][dk*16+l5*8+j]
//   vfr[h][T][dt*4+kb][lane][8] : lane holds V^T[dt*32+l31][T*64+kb*16+l5*8+j]
// In attention every fragment load becomes base+lane*16B = dense 1KB.
// ---------------------------------------------------------------------------
__global__ __launch_bounds__(256) void repack_kernel(
    const unsigned short* __restrict__ kh, const unsigned short* __restrict__ vht,
    unsigned short* __restrict__ kfr, unsigned short* __restrict__ vfr)
{
    const int lane = threadIdx.x & 63;
    const int wid = threadIdx.x >> 6;
    const int l31 = lane & 31;
    const int l5 = lane >> 5;
    const int h = blockIdx.x >> 4;
    const int T = ((blockIdx.x & 15) << 2) + wid;

    const unsigned short* __restrict__ ksrc = kh + ((size_t)h * SEQ + T * 64) * HDIM;
    unsigned short* __restrict__ kdst = kfr + ((size_t)(h * 64 + T)) * 4096 + lane * 8;
    #pragma unroll
    for (int ns = 0; ns < 2; ++ns)
        #pragma unroll
        for (int dk = 0; dk < 4; ++dk) {
            v8bf f = *reinterpret_cast<const v8bf*>(ksrc + (ns * 32 + l31) * HDIM + dk * 16 + l5 * 8);
            *reinterpret_cast<v8bf*>(kdst + (ns * 4 + dk) * 512) = f;
        }

    const unsigned short* __restrict__ vsrc = vht + ((size_t)h * 64) * SEQ;
    unsigned short* __restrict__ vdst = vfr + ((size_t)(h * 64 + T)) * 4096 + lane * 8;
    #pragma unroll
    for (int dt = 0; dt < 2; ++dt)
        #pragma unroll
        for (int kb = 0; kb < 4; ++kb) {
            v8bf f = *reinterpret_cast<const v8bf*>(
                vsrc + (size_t)(dt * 32 + l31) * SEQ + T * 64 + kb * 16 + l5 * 8);
            *reinterpret_cast<v8bf*>(vdst + (dt * 4 + kb) * 512) = f;
        }
}

// ---------------------------------------------------------------------------
// Kernel 3: causal flash attention, swapped-QK^T 32x32, flash-decoding split.
// 1 wave/block, 32 q-rows, KV chunk of <=16 rounds (1024 kv) per wave.
// 5120 balanced waves, no LDS, no barriers. K/V fragment loads are DENSE
// (pre-fragmented kfr/vfr): base + lane*16B, one 1KB instr per fragment.
// ---------------------------------------------------------------------------
__global__ __launch_bounds__(64, 2) void attn_kernel(
    const unsigned short* __restrict__ qh, const unsigned short* __restrict__ kfr,
    const unsigned short* __restrict__ vfr, float* __restrict__ out,
    unsigned short* __restrict__ po, float* __restrict__ ml)
{
    const int lane = threadIdx.x & 63;
    const int l31 = lane & 31;
    const int l5 = lane >> 5;

    const int bid = blockIdx.x;
    const int xcd = bid & 7;                 // HW: consecutive bids round-robin XCDs
    const int idx = bid >> 3;                // 0..639 per XCD
    const int hsel = (idx >= 320) ? 1 : 0;
    const int h = (xcd << 1) | hsel;         // 2 heads per XCD -> K/V L2-resident
    const int r = 319 - (idx - hsel * 320);  // descending: long chunks first

    int qb, c, nc;
    if (r < 32)       { qb = r;                     c = 0;            nc = 1; }
    else if (r < 96)  { qb = 32 + ((r - 32) >> 1);  c = (r - 32) & 1; nc = 2; }
    else if (r < 192) { int rr = r - 96; qb = 64 + rr / 3; c = rr - (qb - 64) * 3; nc = 3; }
    else              { int rr = r - 192; qb = 96 + (rr >> 2); c = rr & 3; nc = 4; }

    const int q0 = qb * 32;
    const int q = q0 + l31;
    const int nt = (q0 + 32 + 63) >> 6;      // total kv-rounds for this q-tile
    const int t0 = c * 16;
    const int t1 = min(t0 + 16, nt);

    const unsigned short* __restrict__ qbase = qh + ((size_t)h * SEQ + q) * HDIM + l5 * 8;
    const unsigned short* __restrict__ kfh = kfr + (size_t)h * 262144 + lane * 8;
    const unsigned short* __restrict__ vfh = vfr + (size_t)h * 262144 + lane * 8;

    v8bf qf[4];
    #pragma unroll
    for (int dk = 0; dk < 4; ++dk)
        qf[dk] = *reinterpret_cast<const v8bf*>(qbase + dk * 16);

    f32x16 of[2] = {};
    float mreg = -INFINITY, lreg = 0.0f;

    auto LOADK = [&](v8bf (&KB)[8], int T) {
        const unsigned short* kp = kfh + (size_t)T * 4096;
        #pragma unroll
        for (int f = 0; f < 8; ++f)
            KB[f] = *reinterpret_cast<const v8bf*>(kp + f * 512);
    };

    auto ROUND = [&](int T, v8bf (&KC)[8], v8bf (&KN)[8]) {
        // V^T fragments (dense 1KB loads; issued early, consumed after softmax)
        v8bf vf[8];
        {
            const unsigned short* vp = vfh + (size_t)T * 4096;
            #pragma unroll
            for (int f = 0; f < 8; ++f)
                vf[f] = *reinterpret_cast<const v8bf*>(vp + f * 512);
        }
        if (T + 1 < t1) LOADK(KN, T + 1);

        // S^T = K Q^T : col=q=l31, row_kv = T*64 + 32ns + (i&3)+8*(i>>2)+4*l5
        f32x16 st[2];
        __builtin_amdgcn_s_setprio(1);
        #pragma unroll
        for (int ns = 0; ns < 2; ++ns) {
            f32x16 acc = {};
            #pragma unroll
            for (int dk = 0; dk < 4; ++dk)
                acc = __builtin_amdgcn_mfma_f32_32x32x16_bf16(KC[ns * 4 + dk], qf[dk], acc, 0, 0, 0);
            st[ns] = acc;
        }
        __builtin_amdgcn_s_setprio(0);

        // causal mask: provably needed only on the globally-last round
        if (T == nt - 1) {
            const int kvb = T * 64 + 4 * l5;
            #pragma unroll
            for (int ns = 0; ns < 2; ++ns)
                #pragma unroll
                for (int i = 0; i < 16; ++i) {
                    int kv = kvb + ns * 32 + (i & 3) + 8 * (i >> 2);
                    if (kv > q) st[ns][i] = -INFINITY;
                }
        }

        // row max: in-lane tree + 1 permlane32_swap
        float t16[16];
        #pragma unroll
        for (int i = 0; i < 16; ++i) t16[i] = fmaxf(st[0][i], st[1][i]);
        #pragma unroll
        for (int i = 0; i < 8; ++i) t16[i] = fmaxf(t16[i], t16[i + 8]);
        #pragma unroll
        for (int i = 0; i < 4; ++i) t16[i] = fmaxf(t16[i], t16[i + 4]);
        float pmax = fmaxf(fmaxf(t16[0], t16[1]), fmaxf(t16[2], t16[3]));
        {
            i32x2 sw = __builtin_amdgcn_permlane32_swap(__float_as_int(pmax), __float_as_int(pmax), false, false);
            pmax = fmaxf(__int_as_float(sw.x), __int_as_float(sw.y));
        }

        // defer-max (T13): rescale only if max grew by > 8 (exp2 domain)
        if (!__all(pmax - mreg <= 8.0f)) {
            float mnew = fmaxf(mreg, pmax);
            float sc = exp2f(mreg - mnew);
            lreg *= sc;
            #pragma unroll
            for (int dt = 0; dt < 2; ++dt)
                #pragma unroll
                for (int i = 0; i < 16; ++i) of[dt][i] *= sc;
            mreg = mnew;
        }

        // exp2 + partial row-sum
        float ps0 = 0.f, ps1 = 0.f, ps2 = 0.f, ps3 = 0.f;
        #pragma unroll
        for (int ns = 0; ns < 2; ++ns)
            #pragma unroll
            for (int i = 0; i < 16; ++i) {
                float p = exp2f(st[ns][i] - mreg);
                st[ns][i] = p;
                if ((i & 3) == 0) ps0 += p; else if ((i & 3) == 1) ps1 += p;
                else if ((i & 3) == 2) ps2 += p; else ps3 += p;
            }
        lreg += (ps0 + ps1) + (ps2 + ps3);

        // P^T B-fragments: cvt_pk + permlane32_swap (T12)
        v8bf pt[4];
        #pragma unroll
        for (int kb = 0; kb < 4; ++kb) {
            int ns = kb >> 1, kp = (kb & 1) * 8;
            int A0 = cvtpk(st[ns][kp + 0], st[ns][kp + 1]);
            int A1 = cvtpk(st[ns][kp + 2], st[ns][kp + 3]);
            int B0 = cvtpk(st[ns][kp + 4], st[ns][kp + 5]);
            int B1 = cvtpk(st[ns][kp + 6], st[ns][kp + 7]);
            i32x2 s0 = __builtin_amdgcn_permlane32_swap(A0, B0, false, false);
            i32x2 s1 = __builtin_amdgcn_permlane32_swap(A1, B1, false, false);
            i32x4 u; u.x = s0.x; u.y = s1.x; u.z = s0.y; u.w = s1.y;
            v8bf p; __builtin_memcpy(&p, &u, 16);
            pt[kb] = p;
        }

        // O^T += V^T P^T
        __builtin_amdgcn_s_setprio(1);
        #pragma unroll
        for (int dt = 0; dt < 2; ++dt)
            #pragma unroll
            for (int kb = 0; kb < 4; ++kb)
                of[dt] = __builtin_amdgcn_mfma_f32_32x32x16_bf16(vf[dt * 4 + kb], pt[kb], of[dt], 0, 0, 0);
        __builtin_amdgcn_s_setprio(0);
    };

    v8bf kA[8], kB[8];
    LOADK(kA, t0);
    int t = t0;
    while (true) {
        ROUND(t, kA, kB);
        if (++t == t1) break;
        ROUND(t, kB, kA);
        if (++t == t1) break;
    }

    // pair-sum l across halves (both halves end with full row-sum)
    {
        i32x2 sw = __builtin_amdgcn_permlane32_swap(__float_as_int(lreg), __float_as_int(lreg), false, false);
        lreg = __int_as_float(sw.x) + __int_as_float(sw.y);
    }

    if (nc == 1) {
        float inv = 1.0f / lreg;
        float* obase = out + (size_t)q * DMODEL + h * HDIM + l5 * 4;
        #pragma unroll
        for (int dt = 0; dt < 2; ++dt)
            #pragma unroll
            for (int g = 0; g < 4; ++g) {
                f32x4 o4;
                o4[0] = of[dt][g * 4 + 0] * inv;
                o4[1] = of[dt][g * 4 + 1] * inv;
                o4[2] = of[dt][g * 4 + 2] * inv;
                o4[3] = of[dt][g * 4 + 3] * inv;
                *reinterpret_cast<f32x4*>(obase + dt * 32 + g * 8) = o4;
            }
    } else {
        const int p = h * 288 + (r - 32);
        unsigned short* pb = po + ((size_t)p * 32 + l31) * 64 + l5 * 4;
        #pragma unroll
        for (int dt = 0; dt < 2; ++dt)
            #pragma unroll
            for (int g = 0; g < 4; ++g) {
                uint2 u;
                u.x = (unsigned)cvtpk(of[dt][g * 4 + 0], of[dt][g * 4 + 1]);
                u.y = (unsigned)cvtpk(of[dt][g * 4 + 2], of[dt][g * 4 + 3]);
                *reinterpret_cast<uint2*>(pb + dt * 32 + g * 8) = u;
            }
        if (l5 == 0) {
            float2 v; v.x = mreg; v.y = lreg;
            reinterpret_cast<float2*>(ml)[(size_t)p * 32 + l31] = v;
        }
    }
}

// ---------------------------------------------------------------------------
// Kernel 4: combine partials for qb>=32 (2..4 chunks per q-tile).
// 1536 blocks x 256 threads (4 rows in parallel).
// ---------------------------------------------------------------------------
__global__ __launch_bounds__(256) void combine_kernel(
    const unsigned short* __restrict__ po, const float* __restrict__ ml,
    float* __restrict__ out)
{
    const int b = blockIdx.x;
    const int h = b / 96;
    const int j = b - h * 96;
    const int qb = 32 + j;
    int nc, r0;
    if (qb < 64)      { nc = 2; r0 = 32 + ((qb - 32) << 1); }
    else if (qb < 96) { nc = 3; r0 = 96 + (qb - 64) * 3; }
    else              { nc = 4; r0 = 192 + ((qb - 96) << 2); }
    const int p0 = h * 288 + (r0 - 32);
    const int d = threadIdx.x & 63;
    const int rg = threadIdx.x >> 6;
    const int q0 = qb * 32;

    for (int row = rg; row < 32; row += 4) {
        float mc[4], lc[4];
        float M = -INFINITY;
        #pragma unroll
        for (int ci = 0; ci < 4; ++ci)
            if (ci < nc) {
                float2 v = reinterpret_cast<const float2*>(ml)[(size_t)(p0 + ci) * 32 + row];
                mc[ci] = v.x; lc[ci] = v.y;
                M = fmaxf(M, v.x);
            }
        float L = 0.0f, O = 0.0f;
        #pragma unroll
        for (int ci = 0; ci < 4; ++ci)
            if (ci < nc) {
                float w = exp2f(mc[ci] - M);
                L += lc[ci] * w;
                unsigned int raw = po[((size_t)(p0 + ci) * 32 + row) * 64 + d];
                union { unsigned int u; float f; } cv; cv.u = raw << 16;
                O += cv.f * w;
            }
        out[(size_t)(q0 + row) * DMODEL + h * HDIM + d] = O / L;
    }
}

extern "C" void kernel_launch(void* const* d_in, const int* in_sizes, int n_in,
                              void* d_out, int out_size, void* d_ws, size_t ws_size,
                              hipStream_t stream) {
    (void)in_sizes; (void)n_in; (void)out_size; (void)ws_size;
    const float* q  = (const float*)d_in[0];
    const float* k  = (const float*)d_in[1];
    const float* v  = (const float*)d_in[2];
    // d_in[3] = mask: tril(ones) -> causal, applied analytically
    const float* Wq = (const float*)d_in[4];
    const float* Wk = (const float*)d_in[5];
    const float* Wv = (const float*)d_in[6];

    // ws layout (po overlays kh+vht, which are dead after repack):
    unsigned short* qh  = (unsigned short*)d_ws;                      // 8.4 MB
    unsigned short* kfr = qh  + (size_t)NHEADS * SEQ * HDIM;          // 8.4 MB
    unsigned short* vfr = kfr + (size_t)NHEADS * SEQ * HDIM;          // 8.4 MB
    unsigned short* kh  = vfr + (size_t)NHEADS * SEQ * HDIM;          // 8.4 MB
    unsigned short* vht = kh  + (size_t)NHEADS * SEQ * HDIM;          // 8.4 MB
    unsigned short* po  = kh;                                         // 18.9 MB (overlay)
    float* ml = (float*)(po + (size_t)NPART * 32 * 64);               // 1.2 MB
    float* out = (float*)d_out;

    dim3 g1(SEQ / 128, DMODEL / 128, 3);
    proj_rope_kernel<<<g1, 256, 0, stream>>>(q, k, v, Wq, Wk, Wv, qh, kh, vht);

    repack_kernel<<<dim3(256), 256, 0, stream>>>(kh, vht, kfr, vfr);

    attn_kernel<<<dim3(16 * 320), 64, 0, stream>>>(qh, kfr, vfr, out, po, ml);

    combine_kernel<<<dim3(16 * 96), 256, 0, stream>>>(po, ml, out);
}